// Round 8
// baseline (491.874 us; speedup 1.0000x reference)
//
#include <hip/hip_runtime.h>
#include <hip/hip_bf16.h>
#include <stdint.h>

// Problem constants (from setup_inputs)
#define T_DIM 2048
#define N_DIM 16
#define I_DIM 1024
#define H_DIM 2048
#define O_DIM 1024
#define K_TAPS 12
#define MROWS (N_DIM * T_DIM)   // 32768 rows of (n,t)
#define BN_EPS 1e-5f

typedef __attribute__((ext_vector_type(8))) short bf16x8;
typedef __attribute__((ext_vector_type(4))) float f32x4;

__device__ __forceinline__ unsigned short f2bf_rne(float f) {
    union { float f; unsigned u; } v; v.f = f;
    unsigned u = v.u;
    unsigned r = u + 0x7fffu + ((u >> 16) & 1u);
    return (unsigned short)(r >> 16);
}

__device__ __forceinline__ float bf2f(unsigned short x) {
    union { unsigned u; float f; } v; v.u = ((unsigned)x) << 16; return v.f;
}

// ---------------- fp32 -> bf16 conversion (vectorized x4) ----------------
__global__ void cvt_kernel(const float* __restrict__ in, unsigned short* __restrict__ out, int n4) {
    int i = blockIdx.x * blockDim.x + threadIdx.x;
    int stride = gridDim.x * blockDim.x;
    for (; i < n4; i += stride) {
        float4 v = ((const float4*)in)[i];
        ushort4 o;
        o.x = f2bf_rne(v.x); o.y = f2bf_rne(v.y);
        o.z = f2bf_rne(v.z); o.w = f2bf_rne(v.w);
        ((ushort4*)out)[i] = o;
    }
}

__device__ __forceinline__ void gload_lds16(const void* g, void* l) {
    __builtin_amdgcn_global_load_lds(
        (const __attribute__((address_space(1))) unsigned int*)g,
        (__attribute__((address_space(3))) unsigned int*)l, 16, 0, 0);
}

// ======================= GEMM1 + conv + BN-stats, fused =======================
// 320-row p-tile (core 256 rows t0..t0+255, halo 32 each side) x 256 h-cols.
// K-loop: 8-phase structure, 9 staging loads/tile (A 5x64rows + B 4x64rows)
// spread 3/3/2/1 over the 4 phases of each group -> counted vmcnt(3) at q0.
// Epilogue: acc (bf16) -> LDS col-major p-tile [col][row], stride 564 B
// (word-stride 141, odd -> conflict-free col-indexed reads), then sliding-window
// conv (taps t+(k-10)*2), BN partial stats, stores ph_f32 + ph_b. p never hits HBM.
__global__ __launch_bounds__(512, 2) void gemm1_conv(
    const unsigned short* __restrict__ A,    // in_b [t*N+n][I] bf16
    const unsigned short* __restrict__ B,    // wv_b [H][I] bf16
    const float* __restrict__ w,             // [12][H]
    float* __restrict__ ph_f32,              // [MROWS][H] fp32 out
    unsigned short* __restrict__ ph_b,       // [MROWS][H] bf16 out
    float* __restrict__ sums)                // [2][H] zeroed
{
    __shared__ char lds[148480];
    // staging: A bufs at {0,40960} (320x128B each), B bufs at 81920+{0,32768}
    // epilogue: p-tile col-major at 0 (256 cols x 564B), stats at 144384 (4KB)

    const int tid  = threadIdx.x;
    const int wid  = tid >> 6;
    const int lane = tid & 63;
    const int wr   = (wid >> 2) * 160;    // wave row offset (2 warps_m, 160 rows each)
    const int wc   = (wid & 3) * 64;      // wave col offset (4 warps_n)
    const int fr   = lane & 15;
    const int fh   = lane >> 4;

    const int nwg = gridDim.x;            // 1024, %8==0
    const int lin = blockIdx.x;
    const int tile = (lin & 7) * (nwg >> 3) + (lin >> 3);
    const int ntx = H_DIM / 256;
    const long c0 = (long)(tile % ntx) * 256;
    const long r0 = (long)(tile / ntx) * 256;
    const int n0 = (int)(r0 / T_DIM);
    const int t0 = (int)(r0 % T_DIM);

    const long bBase = c0 * I_DIM;

    auto stageA = [&](int buf, int ci, int kt) {
        const int lr = ci * 64 + (tid >> 3);          // 0..319
        int t = t0 - 32 + lr;
        t = t < 0 ? 0 : (t >= T_DIM ? T_DIM - 1 : t); // clamp; garbage rows unused
        const int g = (tid & 7) ^ (lr & 7);           // inverse swizzle on source
        const long gelem = ((long)t * N_DIM + n0) * I_DIM + kt * 64 + g * 8;
        gload_lds16((const char*)A + gelem * 2, lds + buf * 40960 + ci * 8192 + tid * 16);
    };
    auto stageB2 = [&](int buf, int si, int kt) {
        const int row = si * 64 + (tid >> 3);
        const int g = (tid & 7) ^ (row & 7);
        const long gelem = bBase + (long)row * I_DIM + kt * 64 + g * 8;
        gload_lds16((const char*)B + gelem * 2, lds + 81920 + buf * 32768 + si * 8192 + tid * 16);
    };
    auto rdA = [&](int buf, int m, int ks) -> bf16x8 {
        const int row = wr + m * 16 + fr;             // 0..319
        const int blk = ks * 4 + fh;
        return *(const bf16x8*)(lds + buf * 40960 + row * 128 + ((blk ^ (row & 7)) << 4));
    };
    auto rdB = [&](int buf, int n, int ks) -> bf16x8 {
        const int row = wc + n * 16 + fr;
        const int blk = ks * 4 + fh;
        return *(const bf16x8*)(lds + 81920 + buf * 32768 + row * 128 + ((blk ^ (row & 7)) << 4));
    };

    f32x4 acc[10][4] = {};

    // prologue: stage tile 0 into buf0 (9 loads/thread)
    stageA(0, 0, 0); stageA(0, 1, 0); stageA(0, 2, 0); stageA(0, 3, 0); stageA(0, 4, 0);
    stageB2(0, 0, 0); stageB2(0, 1, 0); stageB2(0, 2, 0); stageB2(0, 3, 0);

    // m-fragment distribution over the 4 phases: {0,1,2},{3,4,5},{6,7},{8,9}
    for (int i = 0; i < 8; ++i) {
        const int tB = 2 * i + 1;
        const bool haveNext = (i + 1 < 8);

        // ---- group 1 (phases 0-3): compute buf0 (tile 2i); stage buf1 <- tile 2i+1
        {
            bf16x8 bfr[4][2];
#pragma unroll
            for (int q = 0; q < 4; ++q) {
                if (q == 0)      { stageA(1, 0, tB); stageA(1, 1, tB); stageA(1, 2, tB); }
                else if (q == 1) { stageA(1, 3, tB); stageA(1, 4, tB); stageB2(1, 0, tB); }
                else if (q == 2) { stageB2(1, 1, tB); stageB2(1, 2, tB); }
                else             { stageB2(1, 3, tB); }
                const int ms = (q == 0) ? 0 : (q == 1) ? 3 : (q == 2) ? 6 : 8;
                const int mc = (q <= 1) ? 3 : 2;
                bf16x8 af[3][2];
                if (q == 0) {
                    asm volatile("s_waitcnt vmcnt(3)" ::: "memory");
                    __builtin_amdgcn_s_barrier();
#pragma unroll
                    for (int n = 0; n < 4; ++n)
#pragma unroll
                        for (int ks = 0; ks < 2; ++ks) bfr[n][ks] = rdB(0, n, ks);
#pragma unroll
                    for (int mm = 0; mm < 3; ++mm)
#pragma unroll
                        for (int ks = 0; ks < 2; ++ks) af[mm][ks] = rdA(0, ms + mm, ks);
                } else {
#pragma unroll
                    for (int mm = 0; mm < 3; ++mm)
                        if (mm < mc)
#pragma unroll
                            for (int ks = 0; ks < 2; ++ks) af[mm][ks] = rdA(0, ms + mm, ks);
                    __builtin_amdgcn_s_barrier();
                }
                __builtin_amdgcn_s_setprio(1);
#pragma unroll
                for (int mm = 0; mm < 3; ++mm)
                    if (mm < mc)
#pragma unroll
                        for (int n = 0; n < 4; ++n)
#pragma unroll
                            for (int ks = 0; ks < 2; ++ks)
                                acc[ms + mm][n] = __builtin_amdgcn_mfma_f32_16x16x32_bf16(
                                    af[mm][ks], bfr[n][ks], acc[ms + mm][n], 0, 0, 0);
                __builtin_amdgcn_s_setprio(0);
                __builtin_amdgcn_s_barrier();
            }
        }

        // ---- group 2 (phases 4-7): compute buf1 (tile 2i+1); stage buf0 <- tile 2i+2
        {
            const int tN = 2 * i + 2;
            bf16x8 bfr[4][2];
#pragma unroll
            for (int q = 0; q < 4; ++q) {
                if (haveNext) {
                    if (q == 0)      { stageA(0, 0, tN); stageA(0, 1, tN); stageA(0, 2, tN); }
                    else if (q == 1) { stageA(0, 3, tN); stageA(0, 4, tN); stageB2(0, 0, tN); }
                    else if (q == 2) { stageB2(0, 1, tN); stageB2(0, 2, tN); }
                    else             { stageB2(0, 3, tN); }
                }
                const int ms = (q == 0) ? 0 : (q == 1) ? 3 : (q == 2) ? 6 : 8;
                const int mc = (q <= 1) ? 3 : 2;
                bf16x8 af[3][2];
                if (q == 0) {
                    if (haveNext) asm volatile("s_waitcnt vmcnt(3)" ::: "memory");
                    else          asm volatile("s_waitcnt vmcnt(0)" ::: "memory");
                    __builtin_amdgcn_s_barrier();
#pragma unroll
                    for (int n = 0; n < 4; ++n)
#pragma unroll
                        for (int ks = 0; ks < 2; ++ks) bfr[n][ks] = rdB(1, n, ks);
#pragma unroll
                    for (int mm = 0; mm < 3; ++mm)
#pragma unroll
                        for (int ks = 0; ks < 2; ++ks) af[mm][ks] = rdA(1, ms + mm, ks);
                } else {
#pragma unroll
                    for (int mm = 0; mm < 3; ++mm)
                        if (mm < mc)
#pragma unroll
                            for (int ks = 0; ks < 2; ++ks) af[mm][ks] = rdA(1, ms + mm, ks);
                    __builtin_amdgcn_s_barrier();
                }
                __builtin_amdgcn_s_setprio(1);
#pragma unroll
                for (int mm = 0; mm < 3; ++mm)
                    if (mm < mc)
#pragma unroll
                        for (int n = 0; n < 4; ++n)
#pragma unroll
                            for (int ks = 0; ks < 2; ++ks)
                                acc[ms + mm][n] = __builtin_amdgcn_mfma_f32_16x16x32_bf16(
                                    af[mm][ks], bfr[n][ks], acc[ms + mm][n], 0, 0, 0);
                __builtin_amdgcn_s_setprio(0);
                __builtin_amdgcn_s_barrier();
            }
        }
    }

    // ---- epilogue 1: acc -> LDS p-tile (bf16, col-major), rows lr in [12,290)
    // entry e = lr-12 (0..277), addr = col*564 + e*2. C/D: col=fr, row=fh*4+j.
#pragma unroll
    for (int m = 0; m < 10; ++m) {
        const int rb = wr + m * 16 + fh * 4;          // local row base (mult of 4)
        if (rb >= 12 && rb < 290) {
#pragma unroll
            for (int n = 0; n < 4; ++n) {
                const int col = wc + n * 16 + fr;
                unsigned lo = (unsigned)f2bf_rne(acc[m][n][0]) |
                              ((unsigned)f2bf_rne(acc[m][n][1]) << 16);
                unsigned hi = (unsigned)f2bf_rne(acc[m][n][2]) |
                              ((unsigned)f2bf_rne(acc[m][n][3]) << 16);
                char* base = lds + col * 564 + (rb - 12) * 2;
                *(unsigned*)base = lo;
                *(unsigned*)(base + 4) = hi;
            }
        }
    }
    __syncthreads();

    // ---- epilogue 2: sliding-window conv + stats + stores
    // thread = (col 0..255, rhalf 0..1); 128 consecutive core rows, per parity.
    {
        const int col   = tid & 255;
        const int rhalf = tid >> 8;
        const long hcol = c0 + col;
        const char* pcol = lds + col * 564;

        float wkk[12];
#pragma unroll
        for (int k = 0; k < 12; ++k) wkk[k] = w[k * H_DIM + hcol];

        float s1 = 0.f, s2 = 0.f;
#pragma unroll 1
        for (int par = 0; par < 2; ++par) {
            const int tcs = rhalf * 128 + par;        // first core row (local, unshifted)
            float win[12];
#pragma unroll
            for (int j = 0; j < 12; ++j) {
                const int dt = (j - 10) * 2;
                const int tg = t0 + tcs + dt;
                const int e  = 20 + tcs + dt;         // >= 0
                win[j] = ((unsigned)tg < T_DIM)
                         ? bf2f(*(const unsigned short*)(pcol + e * 2)) : 0.f;
            }
#pragma unroll
            for (int u = 0; u < 64; ++u) {
                const int cr = tcs + 2 * u;           // core row 0..255
                float out = win[(u + 10) % 12];       // identity tap x[t]
#pragma unroll
                for (int k = 0; k < 12; ++k) out += wkk[k] * win[(u + k) % 12];

                const long base = (r0 + cr) * (long)H_DIM + hcol;
                ph_f32[base] = out;
                ph_b[base] = f2bf_rne(out);
                s1 += out; s2 += out * out;

                if (u < 63) {                          // fresh tap x[cr+2+2]
                    const int tg2 = t0 + cr + 4;
                    const int e2  = 20 + cr + 4;       // <= 277
                    win[u % 12] = ((unsigned)tg2 < T_DIM)
                                  ? bf2f(*(const unsigned short*)(pcol + e2 * 2)) : 0.f;
                }
            }
        }

        // pair-reduce (rhalf 0/1 share col) then one atomic pair per col
        *(float2*)(lds + 144384 + tid * 8) = make_float2(s1, s2);
        __syncthreads();
        if (tid < 256) {
            float2 o = *(const float2*)(lds + 144384 + (tid + 256) * 8);
            atomicAdd(&sums[hcol], s1 + o.x);
            atomicAdd(&sums[H_DIM + hcol], s2 + o.y);
        }
    }
}

// ---------------- 256x256 8-phase bf16 MFMA GEMM, C = A * B^T ----------------
// (R4-verified version, used for GEMM2 only.)
template<int PERM, int EPI, int KD, int NCOLS>
__global__ __launch_bounds__(512, 2) void gemm256(
    const unsigned short* __restrict__ A,
    const unsigned short* __restrict__ B,
    void* __restrict__ Cout,
    const float* __restrict__ bias)
{
    __shared__ char lds[131072];

    const int tid  = threadIdx.x;
    const int wid  = tid >> 6;
    const int lane = tid & 63;
    const int wr   = (wid >> 2) * 128;
    const int wc   = (wid & 3) * 64;
    const int fr   = lane & 15;
    const int fh   = lane >> 4;

    const int nwg = gridDim.x;
    const int lin = blockIdx.x;
    const int tile = (lin & 7) * (nwg >> 3) + (lin >> 3);
    const int ntx = NCOLS / 256;
    const long c0 = (long)(tile % ntx) * 256;
    const long r0 = (long)(tile / ntx) * 256;

    long aBase, aStride;
    if (PERM) {
        const long n0 = r0 / T_DIM;
        const long t0 = r0 % T_DIM;
        aBase = (t0 * N_DIM + n0) * (long)KD;
        aStride = (long)N_DIM * KD;
    } else {
        aBase = r0 * (long)KD;
        aStride = KD;
    }
    const long bBase = c0 * (long)KD;

    auto stage_half = [&](int buf, int mat, int h, int kt) {
        char* mbase = lds + buf * 65536 + mat * 32768 + h * 16384;
#pragma unroll
        for (int j = 0; j < 2; ++j) {
            const int row = h * 128 + j * 64 + (tid >> 3);
            const int g   = (tid & 7) ^ (row & 7);
            long gelem;
            if (mat == 0) gelem = aBase + (long)row * aStride + (long)kt * 64 + g * 8;
            else          gelem = bBase + (long)row * (long)KD + (long)kt * 64 + g * 8;
            gload_lds16((const char*)(mat == 0 ? A : B) + gelem * 2,
                        mbase + j * 8192 + tid * 16);
        }
    };

    auto rdA = [&](int buf, int m, int ks) -> bf16x8 {
        const int row = wr + m * 16 + fr;
        const int blk = ks * 4 + fh;
        return *(const bf16x8*)(lds + buf * 65536 + row * 128 + ((blk ^ (row & 7)) << 4));
    };
    auto rdB = [&](int buf, int n, int ks) -> bf16x8 {
        const int row = wc + n * 16 + fr;
        const int blk = ks * 4 + fh;
        return *(const bf16x8*)(lds + buf * 65536 + 32768 + row * 128 + ((blk ^ (row & 7)) << 4));
    };

    f32x4 acc[8][4] = {};

    stage_half(0, 0, 0, 0); stage_half(0, 0, 1, 0);
    stage_half(0, 1, 0, 0); stage_half(0, 1, 1, 0);

    const int KT  = KD / 64;
    const int KT2 = KT / 2;
    for (int i = 0; i < KT2; ++i) {
        const int tB = 2 * i + 1;
        const bool haveNext = (i + 1 < KT2);
        bf16x8 bfr[4][2];

#pragma unroll
        for (int q = 0; q < 4; ++q) {
            stage_half(1, q >> 1, q & 1, tB);
            bf16x8 af[2][2];
            if (q == 0) {
                asm volatile("s_waitcnt vmcnt(2)" ::: "memory");
                __builtin_amdgcn_s_barrier();
#pragma unroll
                for (int n = 0; n < 4; ++n)
#pragma unroll
                    for (int ks = 0; ks < 2; ++ks) bfr[n][ks] = rdB(0, n, ks);
#pragma unroll
                for (int mm = 0; mm < 2; ++mm)
#pragma unroll
                    for (int ks = 0; ks < 2; ++ks) af[mm][ks] = rdA(0, q * 2 + mm, ks);
            } else {
#pragma unroll
                for (int mm = 0; mm < 2; ++mm)
#pragma unroll
                    for (int ks = 0; ks < 2; ++ks) af[mm][ks] = rdA(0, q * 2 + mm, ks);
                __builtin_amdgcn_s_barrier();
            }
            __builtin_amdgcn_s_setprio(1);
#pragma unroll
            for (int mm = 0; mm < 2; ++mm)
#pragma unroll
                for (int n = 0; n < 4; ++n)
#pragma unroll
                    for (int ks = 0; ks < 2; ++ks)
                        acc[q * 2 + mm][n] = __builtin_amdgcn_mfma_f32_16x16x32_bf16(
                            af[mm][ks], bfr[n][ks], acc[q * 2 + mm][n], 0, 0, 0);
            __builtin_amdgcn_s_setprio(0);
            __builtin_amdgcn_s_barrier();
        }

#pragma unroll
        for (int q = 0; q < 4; ++q) {
            if (haveNext) stage_half(0, q >> 1, q & 1, 2 * i + 2);
            bf16x8 af[2][2];
            if (q == 0) {
                if (haveNext) asm volatile("s_waitcnt vmcnt(2)" ::: "memory");
                else          asm volatile("s_waitcnt vmcnt(0)" ::: "memory");
                __builtin_amdgcn_s_barrier();
#pragma unroll
                for (int n = 0; n < 4; ++n)
#pragma unroll
                    for (int ks = 0; ks < 2; ++ks) bfr[n][ks] = rdB(1, n, ks);
#pragma unroll
                for (int mm = 0; mm < 2; ++mm)
#pragma unroll
                    for (int ks = 0; ks < 2; ++ks) af[mm][ks] = rdA(1, q * 2 + mm, ks);
            } else {
#pragma unroll
                for (int mm = 0; mm < 2; ++mm)
#pragma unroll
                    for (int ks = 0; ks < 2; ++ks) af[mm][ks] = rdA(1, q * 2 + mm, ks);
                __builtin_amdgcn_s_barrier();
            }
            __builtin_amdgcn_s_setprio(1);
#pragma unroll
            for (int mm = 0; mm < 2; ++mm)
#pragma unroll
                for (int n = 0; n < 4; ++n)
#pragma unroll
                    for (int ks = 0; ks < 2; ++ks)
                        acc[q * 2 + mm][n] = __builtin_amdgcn_mfma_f32_16x16x32_bf16(
                            af[mm][ks], bfr[n][ks], acc[q * 2 + mm][n], 0, 0, 0);
            __builtin_amdgcn_s_setprio(0);
            __builtin_amdgcn_s_barrier();
        }
    }

#pragma unroll
    for (int m = 0; m < 8; ++m) {
        const long orow_base = r0 + wr + m * 16 + fh * 4;
#pragma unroll
        for (int n = 0; n < 4; ++n) {
            const long ocol = c0 + wc + n * 16 + fr;
#pragma unroll
            for (int j = 0; j < 4; ++j) {
                const long orow = orow_base + j;
                float vv = acc[m][n][j];
                if (EPI == 0) {
                    ((unsigned short*)Cout)[orow * NCOLS + ocol] = f2bf_rne(vv);
                } else {
                    vv += bias[ocol];
                    vv = vv > 0.f ? vv : 0.f;
                    ((float*)Cout)[orow * NCOLS + ocol] = vv;
                }
            }
        }
    }
}

// ---------------- BN finalize: s = gamma*rsqrt(var+eps); shift = beta - mean*s ----
__global__ void bn_finalize(const float* __restrict__ sums,
                            const float* __restrict__ gamma,
                            const float* __restrict__ beta,
                            float* __restrict__ sshift) {
    int h = blockIdx.x * blockDim.x + threadIdx.x;
    if (h >= H_DIM) return;
    float mean = sums[h] * (1.f / (float)MROWS);
    float var  = sums[H_DIM + h] * (1.f / (float)MROWS) - mean * mean;
    float s = gamma[h] * rsqrtf(var + BN_EPS);
    sshift[h] = s;
    sshift[H_DIM + h] = beta[h] - mean * s;
}

// wu2[o,h] = bf16(wu[o,h] * s[h])
__global__ void scale_wu(const float* __restrict__ wu,
                         const float* __restrict__ sshift,
                         unsigned short* __restrict__ wu2) {
    int idx = blockIdx.x * blockDim.x + threadIdx.x;
    int stride = gridDim.x * blockDim.x;
    for (; idx < O_DIM * H_DIM; idx += stride) {
        int h = idx & (H_DIM - 1);
        wu2[idx] = f2bf_rne(wu[idx] * sshift[h]);
    }
}

// bias2[o] = bu[o] + sum_h shift[h]*wu[o,h]
__global__ __launch_bounds__(256) void bias2_kernel(
    const float* __restrict__ wu,
    const float* __restrict__ sshift,
    const float* __restrict__ bu,
    float* __restrict__ bias2) {
    const int o = blockIdx.x;
    float part = 0.f;
    for (int h = threadIdx.x; h < H_DIM; h += 256)
        part += sshift[H_DIM + h] * wu[(long)o * H_DIM + h];
#pragma unroll
    for (int off = 32; off > 0; off >>= 1) part += __shfl_down(part, off, 64);
    __shared__ float red[4];
    const int wv = threadIdx.x >> 6, lane = threadIdx.x & 63;
    if (lane == 0) red[wv] = part;
    __syncthreads();
    if (threadIdx.x == 0) bias2[o] = bu[o] + red[0] + red[1] + red[2] + red[3];
}

extern "C" void kernel_launch(void* const* d_in, const int* in_sizes, int n_in,
                              void* d_out, int out_size, void* d_ws, size_t ws_size,
                              hipStream_t stream) {
    const float* inputs = (const float*)d_in[0];   // [T,N,I]
    const float* wv     = (const float*)d_in[1];   // [H,I]
    const float* gamma  = (const float*)d_in[2];   // [H]
    const float* beta   = (const float*)d_in[3];   // [H]
    const float* wu     = (const float*)d_in[4];   // [O,H]
    const float* bu     = (const float*)d_in[5];   // [O]
    const float* mw     = (const float*)d_in[6];   // [K,H]

    float* out_h  = (float*)d_out;                           // [N,T,O]
    float* out_ph = out_h + (size_t)MROWS * O_DIM;           // [N,T,H]

    char* ws = (char*)d_ws;
    unsigned short* ph_b  = (unsigned short*)ws;                     // 134,217,728 B
    unsigned short* in_b  = (unsigned short*)(ws + 134217728);       //  67,108,864 B
    unsigned short* wv_b  = (unsigned short*)(ws + 201326592);       //   4,194,304 B
    unsigned short* wu2_b = (unsigned short*)(ws + 205520896);       //   4,194,304 B
    float* sums   = (float*)(ws + 209715200);                        //      16,384 B
    float* sshift = (float*)(ws + 209731584);                        //      16,384 B
    float* bias2  = (float*)(ws + 209747968);                        //       4,096 B

    hipMemsetAsync(sums, 0, 2 * H_DIM * sizeof(float), stream);

    // 1. convert inputs / wv to bf16
    cvt_kernel<<<2048, 256, 0, stream>>>(inputs, in_b, (T_DIM * N_DIM * I_DIM) / 4);
    cvt_kernel<<<512, 256, 0, stream>>>(wv, wv_b, (H_DIM * I_DIM) / 4);

    // 2. fused GEMM1 + conv + BN stats: writes p_hatt (fp32 + bf16) directly
    gemm1_conv<<<(MROWS / 256) * (H_DIM / 256), 512, 0, stream>>>(
        in_b, wv_b, mw, out_ph, ph_b, sums);

    // 3. BN finalize + fold into GEMM2 weights/bias
    bn_finalize<<<(H_DIM + 255) / 256, 256, 0, stream>>>(sums, gamma, beta, sshift);
    scale_wu<<<2048, 256, 0, stream>>>(wu, sshift, wu2_b);
    bias2_kernel<<<O_DIM, 256, 0, stream>>>(wu, sshift, bu, bias2);

    // 4. GEMM2: h = relu(ph_b @ wu2^T + bias2) -> out_h
    gemm256<0, 1, H_DIM, O_DIM><<<(MROWS / 256) * (O_DIM / 256), 512, 0, stream>>>(
        ph_b, wu2_b, (void*)out_h, bias2);
}